// Round 3
// baseline (160.929 us; speedup 1.0000x reference)
//
#include <hip/hip_runtime.h>
#include <cstdint>
#include <cstddef>

// ManualChebConv: out[b,n,fo] = sum_k Zk[b] @ W[k] + bias
//   Z0 = x, Z1 = L@x, Zk = 2*L@Z_{k-1} - Z_{k-2}, K=5
// B=1024, N=512, F_in=16, F_out=8. L symmetric 512x512 fp32.
//
// R3 = R2 design with ushort8 compile fix (HIP has no ushort8 -> own typedef).
// 1 block per 4 batches (256 blocks), 1024 threads = 16 waves -> 4 waves/SIMD
// (R1 had 8 waves/CU, latency-bound: MfmaUtil 15%, VALUBusy 10%). Each wave
// owns mi=2 M-tiles. Z in LDS bf16, transposed Z^T[col][n], stride 520.
// z1 offset +16 elems (8 banks) to kill z0/z1 bank aliasing in epilogue.
// K-loop software-pipelined: B-frags (LDS) depth 1, A-frags (global,
// L2-resident bf16 L) depth 2.

typedef __attribute__((ext_vector_type(8))) short    frag_ab;  // 8 bf16
typedef __attribute__((ext_vector_type(4))) float    frag_cd;  // 4 fp32
typedef __attribute__((ext_vector_type(8))) uint16_t u16x8;

constexpr int BN    = 512;        // N
constexpr int FIN   = 16;
constexpr int FOUT  = 8;
constexpr int BT    = 4;          // batches per block
constexpr int NCOLS = BT * FIN;   // 64 combined cols
constexpr int LDST  = BN + 8;     // 520 bf16 padded stride (16B aligned)
constexpr int ZBUF  = NCOLS * LDST;  // 33280 elements per buffer
constexpr int ZOFF  = 16;         // z1 offset: 32 B = 8-bank shift

__device__ __forceinline__ uint16_t f2bf(float f) {
    uint32_t u = __builtin_bit_cast(uint32_t, f);
    u += 0x7FFFu + ((u >> 16) & 1u);          // round-to-nearest-even
    return (uint16_t)(u >> 16);
}
__device__ __forceinline__ float bf2f(uint16_t h) {
    uint32_t u = ((uint32_t)h) << 16;
    return __builtin_bit_cast(float, u);
}

__global__ void cvtL(const float* __restrict__ Lf, uint16_t* __restrict__ Lb) {
    int i = blockIdx.x * 256 + threadIdx.x;   // 128 blocks x 256 thr x 8 elems
    const float4* p = reinterpret_cast<const float4*>(Lf) + i * 2;
    float4 u0 = p[0], u1 = p[1];
    u16x8 o;
    o[0] = f2bf(u0.x); o[1] = f2bf(u0.y);
    o[2] = f2bf(u0.z); o[3] = f2bf(u0.w);
    o[4] = f2bf(u1.x); o[5] = f2bf(u1.y);
    o[6] = f2bf(u1.z); o[7] = f2bf(u1.w);
    *(reinterpret_cast<u16x8*>(Lb) + i) = o;
}

__global__ __launch_bounds__(1024, 1)
void cheb_kernel(const float* __restrict__ x, const uint16_t* __restrict__ Lb,
                 const float* __restrict__ W, const float* __restrict__ bvec,
                 float* __restrict__ out) {
    __shared__ uint16_t lds[2 * ZBUF + ZOFF];   // 133,152 B
    uint16_t* z0 = lds;
    uint16_t* z1 = lds + ZBUF + ZOFF;

    const int tid  = threadIdx.x;
    const int wave = tid >> 6;                // 0..15
    const int lane = tid & 63;
    const int lr   = lane & 15;               // A-row / B-col / D-col within tile
    const int q    = lane >> 4;               // quad

    // ---------------- stage x -> Z0^T (bf16) in z0 ----------------
    const float4* x4 = reinterpret_cast<const float4*>(x + (size_t)blockIdx.x * (BT * BN * FIN));
    {
        int a   = tid;                        // 1024 assignments, one each
        int f0g = a & 3;
        int n8  = (a >> 2) & 63;
        int bl  = a >> 8;
        int jb  = bl * 2048 + n8 * 32 + f0g;
        float4 v[8];
#pragma unroll
        for (int r = 0; r < 8; ++r) v[r] = x4[jb + r * 4];
        int cb = bl * 16 + f0g * 4;
        int nb = n8 * 8;
#pragma unroll
        for (int w = 0; w < 4; ++w) {
            frag_ab pk;
#pragma unroll
            for (int r = 0; r < 8; ++r)
                pk[r] = (short)f2bf(reinterpret_cast<const float*>(&v[r])[w]);
            *reinterpret_cast<frag_ab*>(&z0[(cb + w) * LDST + nb]) = pk;
        }
    }

    // ---------------- W pair B-fragments + bias ----------------
    frag_ab wf[3];
#pragma unroll
    for (int p = 0; p < 3; ++p) {
        frag_ab t;
#pragma unroll
        for (int jj = 0; jj < 8; ++jj) {
            int k   = q * 8 + jj;
            int ki  = p * 2 + (k >> 4);
            int fin = k & 15;
            float val = (lr < 8 && ki < 5) ? W[ki * (FIN * FOUT) + fin * FOUT + lr] : 0.0f;
            t[jj] = (short)f2bf(val);
        }
        wf[p] = t;
    }
    const float bv = (lr < 8) ? bvec[lr] : 0.0f;

    frag_cd accOut[2][4] = {};                // [mi][bt] out tiles

    // A-frag base: L[row = mt*16+lr][ks*32 + q*8], mt = wave + mi*16
    const uint16_t* aBase0 = Lb + ((wave +  0) * 16 + lr) * BN + q * 8;
    const uint16_t* aBase1 = Lb + ((wave + 16) * 16 + lr) * BN + q * 8;

    // One application: dst = L@cur (first) or 2*L@cur - dst (in-place).
    auto app = [&](const uint16_t* cur, uint16_t* dst, bool first) {
        frag_cd acc[2][4] = {};               // [mi][ct]
        const uint16_t* bBase = cur + lr * LDST + q * 8;
        frag_ab bf_[2][4];                    // LDS prefetch depth 1
        frag_ab af_[3][2];                    // global prefetch depth 2

        auto loadB = [&](int ks, int buf) {
#pragma unroll
            for (int ct = 0; ct < 4; ++ct)
                bf_[buf][ct] = *reinterpret_cast<const frag_ab*>(
                    bBase + ct * (16 * LDST) + ks * 32);
        };
        auto loadA = [&](int ks, int buf) {
            af_[buf][0] = *reinterpret_cast<const frag_ab*>(aBase0 + ks * 32);
            af_[buf][1] = *reinterpret_cast<const frag_ab*>(aBase1 + ks * 32);
        };

        loadB(0, 0);
        loadA(0, 0);
        loadA(1, 1);
#pragma unroll
        for (int ks = 0; ks < 16; ++ks) {
            const int cb = ks & 1, ab = ks % 3;
            if (ks < 15) loadB(ks + 1, cb ^ 1);
            if (ks < 14) loadA(ks + 2, (ks + 2) % 3);
#pragma unroll
            for (int mi = 0; mi < 2; ++mi)
#pragma unroll
                for (int ct = 0; ct < 4; ++ct)
                    acc[mi][ct] = __builtin_amdgcn_mfma_f32_16x16x32_bf16(
                        af_[ab][mi], bf_[cb][ct], acc[mi][ct], 0, 0, 0);
        }

        // writeback: lane holds rows q*4+r, col ct*16+lr (RMW same lane -> race-free)
#pragma unroll
        for (int mi = 0; mi < 2; ++mi) {
            int row0 = (wave + mi * 16) * 16 + q * 4;
#pragma unroll
            for (int ct = 0; ct < 4; ++ct) {
                uint16_t* dp = dst + (ct * 16 + lr) * LDST + row0;
                float v0 = acc[mi][ct][0], v1 = acc[mi][ct][1];
                float v2 = acc[mi][ct][2], v3 = acc[mi][ct][3];
                if (!first) {
                    ushort4 pv = *reinterpret_cast<const ushort4*>(dp);
                    v0 = 2.f * v0 - bf2f(pv.x); v1 = 2.f * v1 - bf2f(pv.y);
                    v2 = 2.f * v2 - bf2f(pv.z); v3 = 2.f * v3 - bf2f(pv.w);
                }
                ushort4 nv;
                nv.x = f2bf(v0); nv.y = f2bf(v1); nv.z = f2bf(v2); nv.w = f2bf(v3);
                *reinterpret_cast<ushort4*>(dp) = nv;
            }
        }
    };

    // Paired epilogue: accOut += [bufA | bufB](A-layout) @ wfr
    auto epi = [&](const uint16_t* bA, const uint16_t* bB, frag_ab wfr) {
        const uint16_t* base = (q < 2) ? bA : bB;
        int finb = (q & 1) * 8;
#pragma unroll
        for (int mi = 0; mi < 2; ++mi) {
            int n = (wave + mi * 16) * 16 + lr;
#pragma unroll
            for (int bt = 0; bt < 4; ++bt) {
                const uint16_t* pp = base + (bt * 16 + finb) * LDST + n;
                frag_ab afr;
#pragma unroll
                for (int jj = 0; jj < 8; ++jj) afr[jj] = (short)pp[jj * LDST];
                accOut[mi][bt] = __builtin_amdgcn_mfma_f32_16x16x32_bf16(
                    afr, wfr, accOut[mi][bt], 0, 0, 0);
            }
        }
    };

    __syncthreads();
    app(z0, z1, true);        // Z1 -> z1
    __syncthreads();
    epi(z0, z1, wf[0]);       // out += Z0@W0 + Z1@W1
    __syncthreads();
    app(z1, z0, false);       // Z2 -> z0 (over Z0)
    __syncthreads();
    app(z0, z1, false);       // Z3 -> z1 (over Z1)
    __syncthreads();
    epi(z0, z1, wf[1]);       // out += Z2@W2 + Z3@W3
    __syncthreads();
    app(z1, z0, false);       // Z4 -> z0 (over Z2)
    __syncthreads();
    epi(z0, z0, wf[2]);       // out += Z4@W4 (second half weights zero)

    // ---------------- store ----------------
    if (lr < 8) {
        float* ob = out + (size_t)blockIdx.x * BT * BN * FOUT;
#pragma unroll
        for (int mi = 0; mi < 2; ++mi) {
            int row0 = (wave + mi * 16) * 16 + q * 4;
#pragma unroll
            for (int bt = 0; bt < 4; ++bt) {
                float* op = ob + bt * (BN * FOUT) + row0 * FOUT + lr;
                op[0 * FOUT] = accOut[mi][bt][0] + bv;
                op[1 * FOUT] = accOut[mi][bt][1] + bv;
                op[2 * FOUT] = accOut[mi][bt][2] + bv;
                op[3 * FOUT] = accOut[mi][bt][3] + bv;
            }
        }
    }
}

extern "C" void kernel_launch(void* const* d_in, const int* in_sizes, int n_in,
                              void* d_out, int out_size, void* d_ws, size_t ws_size,
                              hipStream_t stream) {
    const float* x  = (const float*)d_in[0];   // [1024,512,16]
    const float* Lf = (const float*)d_in[1];   // [512,512]
    const float* W  = (const float*)d_in[2];   // [5,16,8]
    const float* bv = (const float*)d_in[3];   // [8]
    float* out = (float*)d_out;                // [1024,512,8]

    uint16_t* Lb = (uint16_t*)d_ws;            // 512 KB bf16 copy of L
    cvtL<<<dim3(128), dim3(256), 0, stream>>>(Lf, Lb);
    cheb_kernel<<<dim3(256), dim3(1024), 0, stream>>>(x, Lb, W, bv, out);
}